// Round 3
// baseline (2002.616 us; speedup 1.0000x reference)
//
#include <hip/hip_runtime.h>

// SineLSTM R3: kill the LDS-broadcast bottleneck.
// R2 read h from LDS 150x per wave per step as wave-uniform ds_read_b32
// broadcasts -> LDS return BW (128B/clk/CU) saturated at ~2400 cyc/step,
// VALUBusy stuck at 33%. R3: h is read ONCE per wave lane-distributed
// (lane k holds h[k]) and broadcast via v_readlane -> SGPR -> v_fmac
// (SGPR src). 150 ds_read -> 3 ds_read per wave per step.
// Gate activations fold into the G-phase (sig(v)=1-1/(e^v+1),
// tanh(v)=1-2/(e^2v+1): act = 1 - m/(e^{m*v}+1), one exp, one select).

#define Hh   50
#define G4   200
#define TLEN 1024

__device__ __forceinline__ float rlf(int v, int k) {
    return __int_as_float(__builtin_amdgcn_readlane(v, k));
}

extern "C" __global__ __launch_bounds__(256, 2)
void sine_lstm_kernel(const float* __restrict__ x,
                      const float* __restrict__ W_ih1,
                      const float* __restrict__ W_hh1,
                      const float* __restrict__ b_ih1,
                      const float* __restrict__ b_hh1,
                      const float* __restrict__ W_ih2,
                      const float* __restrict__ W_hh2,
                      const float* __restrict__ b_ih2,
                      const float* __restrict__ b_hh2,
                      const float* __restrict__ W_lin,
                      const float* __restrict__ b_lin,
                      const int*   __restrict__ predict_p,
                      float* __restrict__ out,
                      int T)
{
    __shared__ __align__(16) float x_lds[TLEN];
    __shared__ __align__(16) float h1[64], c1v[64], h2[64], c2v[64];
    __shared__ __align__(16) float g1[G4], g2[G4];   // pre-activated gates
    __shared__ float o_lds;

    const int tid = threadIdx.x;
    const int b   = blockIdx.x;            // one batch row per block
    const int predict = *predict_p;
    const int S = T + predict;

    // ---- stage x row into LDS (coalesced) ----
    for (int i = tid; i < TLEN; i += 256)
        x_lds[i] = x[(size_t)b * T + i];
    // ---- zero states (all 64 lanes: lanes 50..63 are read lane-distributed) ----
    if (tid < 64) { h1[tid] = 0.0f; c1v[tid] = 0.0f; h2[tid] = 0.0f; c2v[tid] = 0.0f; }
    if (tid == 0) o_lds = 0.0f;

    // ---- per-thread weight rows (unified VGPR/AGPR-resident) ----
    const int j  = tid;
    const int jw = (j < G4) ? j : (G4 - 1);          // clamp so all lanes load valid data
    float w1[Hh], wi2[Hh], wh2[Hh];
    const float wih1_j = W_ih1[jw];
    const float b1_j   = b_ih1[jw] + b_hh1[jw];
    const float b2_j   = b_ih2[jw] + b_hh2[jw];
    #pragma unroll
    for (int k = 0; k < Hh; ++k) {
        w1[k]  = W_hh1[jw * Hh + k];
        wi2[k] = W_ih2[jw * Hh + k];
        wh2[k] = W_hh2[jw * Hh + k];
    }
    // activation selector: gate rows [100,150) are 'g' (tanh), others sigmoid
    const float mgate = (jw >= 2 * Hh && jw < 3 * Hh) ? 2.0f : 1.0f;

    const int wv = tid >> 6;               // wave id 0..3
    const int ln = tid & 63;               // lane
    const float wlin_l = (ln < Hh) ? W_lin[ln] : 0.0f;
    const float blin   = b_lin[0];

    __syncthreads();

    for (int s = 0; s < S; ++s) {
        // ======== G1: one lane-distributed read of h1, readlane broadcast ========
        {
            const float xin = (s < T) ? x_lds[s] : o_lds;
            const int vh = __float_as_int(h1[ln]);   // 1 ds_read_b32 per wave
            float a0 = b1_j + xin * wih1_j, a1 = 0.0f, a2 = 0.0f, a3 = 0.0f;
            #pragma unroll
            for (int k = 0; k < 48; k += 4) {
                a0 += w1[k]     * rlf(vh, k);
                a1 += w1[k + 1] * rlf(vh, k + 1);
                a2 += w1[k + 2] * rlf(vh, k + 2);
                a3 += w1[k + 3] * rlf(vh, k + 3);
            }
            a0 += w1[48] * rlf(vh, 48);
            a1 += w1[49] * rlf(vh, 49);
            const float gsum = (a0 + a2) + (a1 + a3);
            // fused activation: sig(v)=1-1/(e^v+1); tanh(v)=1-2/(e^2v+1)
            const float act = 1.0f - mgate * __fdividef(1.0f, __expf(mgate * gsum) + 1.0f);
            if (j < G4) g1[j] = act;
        }
        __syncthreads();   // B1: g1 complete

        // ======== U1: wave0 lanes<50 update layer-1 state ========
        if (wv == 0 && ln < Hh) {
            const float iA = g1[ln], fA = g1[ln + Hh], gA = g1[ln + 2 * Hh], oA = g1[ln + 3 * Hh];
            const float cn = fA * c1v[ln] + iA * gA;
            c1v[ln] = cn;
            const float th = 1.0f - __fdividef(2.0f, __expf(2.0f * cn) + 1.0f);
            h1[ln] = oA * th;
        }
        __syncthreads();   // B2: h1 complete

        // wave1 preloads c2 for redundant U2b (c2v stable between B2 and B3)
        float cp2 = 0.0f;
        if (wv == 1) cp2 = c2v[ln];

        // ======== G2: two lane-distributed reads, readlane broadcast ========
        {
            const int vh1n = __float_as_int(h1[ln]);
            const int vh2  = __float_as_int(h2[ln]);
            float a0 = b2_j, a1 = 0.0f, a2 = 0.0f, a3 = 0.0f;
            #pragma unroll
            for (int k = 0; k < 48; k += 4) {
                a0 += wi2[k]     * rlf(vh1n, k);
                a1 += wi2[k + 1] * rlf(vh1n, k + 1);
                a2 += wi2[k + 2] * rlf(vh1n, k + 2);
                a3 += wi2[k + 3] * rlf(vh1n, k + 3);
            }
            a0 += wi2[48] * rlf(vh1n, 48);
            a1 += wi2[49] * rlf(vh1n, 49);
            #pragma unroll
            for (int k = 0; k < 48; k += 4) {
                a0 += wh2[k]     * rlf(vh2, k);
                a1 += wh2[k + 1] * rlf(vh2, k + 1);
                a2 += wh2[k + 2] * rlf(vh2, k + 2);
                a3 += wh2[k + 3] * rlf(vh2, k + 3);
            }
            a0 += wh2[48] * rlf(vh2, 48);
            a1 += wh2[49] * rlf(vh2, 49);
            const float gsum = (a0 + a2) + (a1 + a3);
            const float act = 1.0f - mgate * __fdividef(1.0f, __expf(mgate * gsum) + 1.0f);
            if (j < G4) g2[j] = act;
        }
        __syncthreads();   // B3: g2 complete

        // ======== U2a: wave0 = layer-2 state update ========
        if (wv == 0 && ln < Hh) {
            const float iA = g2[ln], fA = g2[ln + Hh], gA = g2[ln + 2 * Hh], oA = g2[ln + 3 * Hh];
            const float cn = fA * c2v[ln] + iA * gA;
            c2v[ln] = cn;
            const float th = 1.0f - __fdividef(2.0f, __expf(2.0f * cn) + 1.0f);
            h2[ln] = oA * th;
        }
        // ======== U2b: wave1 = output dot (redundant activations) ========
        if (wv == 1) {
            float part = 0.0f;
            if (ln < Hh) {
                const float iA = g2[ln], fA = g2[ln + Hh], gA = g2[ln + 2 * Hh], oA = g2[ln + 3 * Hh];
                const float cn = fA * cp2 + iA * gA;
                const float th = 1.0f - __fdividef(2.0f, __expf(2.0f * cn) + 1.0f);
                part = (oA * th) * wlin_l;
            }
            #pragma unroll
            for (int off = 32; off > 0; off >>= 1)
                part += __shfl_down(part, off);
            if (ln == 0) {
                const float o = part + blin;
                out[(size_t)b * S + s] = o;
                o_lds = o;
            }
        }
        // B4 only needed once o_lds feeds the next step's G1 (predict phase)
        if (s >= T - 1) __syncthreads();
        // steady-state hazard check (no B4): g1(s+1) writers passed B3(s),
        // U1(s)'s g1 reads were before B2(s); g2(s+1) writes happen after
        // B2(s+1) which follows wave0/1's U2(s) g2 reads; h2/c2 writes at
        // U2a(s) are read in G2(s+1) after B1+B2(s+1).
    }
}

extern "C" void kernel_launch(void* const* d_in, const int* in_sizes, int n_in,
                              void* d_out, int out_size, void* d_ws, size_t ws_size,
                              hipStream_t stream) {
    const float* x      = (const float*)d_in[0];
    const float* W_ih1  = (const float*)d_in[1];
    const float* W_hh1  = (const float*)d_in[2];
    const float* b_ih1  = (const float*)d_in[3];
    const float* b_hh1  = (const float*)d_in[4];
    const float* W_ih2  = (const float*)d_in[5];
    const float* W_hh2  = (const float*)d_in[6];
    const float* b_ih2  = (const float*)d_in[7];
    const float* b_hh2  = (const float*)d_in[8];
    const float* W_lin  = (const float*)d_in[9];
    const float* b_lin  = (const float*)d_in[10];
    const int*   pred   = (const int*)d_in[11];
    float* out = (float*)d_out;

    const int B = 512;                 // fixed by setup_inputs
    const int T = in_sizes[0] / B;     // 1024

    dim3 grid(B), block(256);
    hipLaunchKernelGGL(sine_lstm_kernel, grid, block, 0, stream,
                       x, W_ih1, W_hh1, b_ih1, b_hh1,
                       W_ih2, W_hh2, b_ih2, b_hh2,
                       W_lin, b_lin, pred, out, T);
}